// Round 2
// baseline (497.180 us; speedup 1.0000x reference)
//
#include <hip/hip_runtime.h>
#include <hip/hip_bf16.h>

#define B_N 65536

typedef __attribute__((ext_vector_type(8))) __bf16 bf16x8;
typedef __attribute__((ext_vector_type(8))) unsigned short ushort8;
typedef __attribute__((ext_vector_type(4))) float f32x4;
typedef __attribute__((ext_vector_type(2))) unsigned uintx2;
typedef __attribute__((ext_vector_type(4))) unsigned uintx4;

// ---------- ws layout (bytes) ----------
// 0     : unsigned max|time_delta| bits (atomicMax target; memset to 0 first)
// 64    : WzT  bf16 [128][64]   Wz = W1[0:64,:] transposed
// 16448 : W2T  bf16 [128][128]
// 49216 : W3T  bf16 [64][128]

__device__ __forceinline__ unsigned short f2bf(float f) {
    unsigned u = __float_as_uint(f);
    u += 0x7FFFu + ((u >> 16) & 1u);   // RNE
    return (unsigned short)(u >> 16);
}

#if defined(__has_builtin)
#if __has_builtin(__builtin_amdgcn_cvt_pk_bf16_f32)
#define HAVE_PK_BF16 1
#endif
#endif

#ifdef HAVE_PK_BF16
__device__ __forceinline__ unsigned pk2(float a, float b) {
    return __builtin_bit_cast(unsigned, __builtin_amdgcn_cvt_pk_bf16_f32(a, b));
}
#else
__device__ __forceinline__ unsigned pk2(float a, float b) {
    return (unsigned)f2bf(a) | ((unsigned)f2bf(b) << 16);
}
#endif

__device__ __forceinline__ float fast_tanh(float x) {
    float e = __expf(2.0f * x);
    return fmaf(-2.0f, __builtin_amdgcn_rcpf(e + 1.0f), 1.0f);
}

// ---------- kernel 1: fused max|td| reduction + weight transpose to bf16 ----------
__global__ void k_prep(const float* __restrict__ td, const float* __restrict__ W1,
                       const float* __restrict__ W2, const float* __restrict__ W3,
                       unsigned* __restrict__ ws) {
    const int stride = gridDim.x * blockDim.x;
    int i0 = blockIdx.x * blockDim.x + threadIdx.x;

    float m = 0.0f;
    for (int i = i0; i < B_N; i += stride) m = fmaxf(m, fabsf(td[i]));
#pragma unroll
    for (int o = 32; o; o >>= 1) m = fmaxf(m, __shfl_down(m, o));
    if ((threadIdx.x & 63) == 0) atomicMax(ws, __float_as_uint(m));

    unsigned short* wsb = (unsigned short*)((char*)ws + 64);
    const int total = 8192 + 16384 + 8192;
    for (int i = i0; i < total; i += stride) {
        float v;
        int o = i;
        if (o < 8192) {                       // WzT[n][k] = W1[k][n]
            int n = o >> 6, k = o & 63;
            v = W1[k * 128 + n];
        } else if (o < 8192 + 16384) {        // W2T[n][k] = W2[k][n]
            o -= 8192;
            int n = o >> 7, k = o & 127;
            v = W2[k * 128 + n];
        } else {                              // W3T[n][k] = W3[k][n]
            o -= 8192 + 16384;
            int n = o >> 7, k = o & 127;
            v = W3[k * 64 + n];
        }
        wsb[i] = f2bf(v);
    }
}

// ---------- kernel 2: the ODE solver ----------
// block = 256 = 4 waves; wave owns 16 rows; grid = 65536/64 = 1024
// Transposed-domain MFMA: D = Wfrag(A) * act(B) -> D[neuron][batch]
// => lane (b = lane&15) holds 4 CONSECUTIVE neurons (q*4+r) per 16-tile:
//    packed cvt + ds_write_b64 instead of 4 scalar b16 writes.
__launch_bounds__(256, 2)
__global__ void k_main(const float* __restrict__ z_in, const float* __restrict__ td,
                       const float* __restrict__ W1, const float* __restrict__ b1,
                       const float* __restrict__ b2, const float* __restrict__ b3,
                       const void* __restrict__ ws, float* __restrict__ out) {
    __shared__ __align__(16) unsigned short WzL[128 * 72];    // 18432 B
    __shared__ __align__(16) unsigned short W3L[64 * 136];    // 17408 B
    __shared__ __align__(16) unsigned short hS[4][16 * 136];  // 17408 B (per-wave)
    __shared__ __align__(16) float b1tW[4][128];              // 2048 B (per-wave)

    const unsigned* wsu = (const unsigned*)ws;
    const unsigned short* wzg = (const unsigned short*)((const char*)ws + 64);
    const unsigned short* w2g = wzg + 8192;
    const unsigned short* w3g = wzg + 24576;

    const int tid = threadIdx.x;

    for (int c = tid; c < 1024; c += 256) {          // stage WzT
        int n = c >> 3, k8 = (c & 7) << 3;
        *(ushort8*)&WzL[n * 72 + k8] = *(const ushort8*)&wzg[n * 64 + k8];
    }
    for (int c = tid; c < 1024; c += 256) {          // stage W3T
        int n = c >> 4, k8 = (c & 15) << 3;
        *(ushort8*)&W3L[n * 136 + k8] = *(const ushort8*)&w3g[n * 128 + k8];
    }
    __syncthreads();

    const float maxab = __uint_as_float(wsu[0]);
    const int steps = (int)ceil((double)maxab / 0.1);

    const int wave = tid >> 6;
    const int lane = tid & 63;
    const int q = lane >> 4;
    const int b = lane & 15;                  // batch row (B/C/D) == weight row (A)
    const int row = blockIdx.x * 64 + wave * 16 + b;
    unsigned short* hw = hS[wave];
    float* b1t = b1tW[wave];

    // z state in fp32, B-fragment layout: zr[kt*8+j] = z[row][kt*32 + q*8 + j]
    float zr[16];
#pragma unroll
    for (int kt = 0; kt < 2; ++kt) {
        const float4* p = (const float4*)(z_in + (size_t)row * 64 + kt * 32 + q * 8);
        float4 a = p[0], c = p[1];
        zr[kt * 8 + 0] = a.x; zr[kt * 8 + 1] = a.y; zr[kt * 8 + 2] = a.z; zr[kt * 8 + 3] = a.w;
        zr[kt * 8 + 4] = c.x; zr[kt * 8 + 5] = c.y; zr[kt * 8 + 6] = c.z; zr[kt * 8 + 7] = c.w;
    }
    const float dtr = (steps > 0) ? (td[row] / (float)steps) : 0.0f;

    // W2T A-fragments cached in registers/AGPRs (32 frags * 4 regs = 128)
    bf16x8 w2f[8][4];
#pragma unroll
    for (int n0 = 0; n0 < 8; ++n0)
#pragma unroll
        for (int kt = 0; kt < 4; ++kt)
            w2f[n0][kt] = __builtin_bit_cast(
                bf16x8, *(const ushort8*)&w2g[(n0 * 16 + b) * 128 + kt * 32 + q * 8]);

    // b2/b3 as packed bf16 pairs (neuron = n0*16 + q*4 + r)
    unsigned b2p[16], b3p[8];
#pragma unroll
    for (int n0 = 0; n0 < 8; ++n0) {
        f32x4 v = *(const f32x4*)&b2[n0 * 16 + q * 4];
        b2p[n0 * 2] = pk2(v[0], v[1]);
        b2p[n0 * 2 + 1] = pk2(v[2], v[3]);
    }
#pragma unroll
    for (int n0 = 0; n0 < 4; ++n0) {
        f32x4 v = *(const f32x4*)&b3[n0 * 16 + q * 4];
        b3p[n0 * 2] = pk2(v[0], v[1]);
        b3p[n0 * 2 + 1] = pk2(v[2], v[3]);
    }
    // layer-1 bias: this lane owns entries 2*lane, 2*lane+1 of b1t
    const float b1a = b1[lane * 2], b1b = b1[lane * 2 + 1];
    const float wta = W1[64 * 128 + lane * 2], wtb = W1[64 * 128 + lane * 2 + 1];

    for (int s = 0; s < steps; ++s) {
        const float t = (float)s * 0.1f;

        // per-step layer-1 bias vector into per-wave LDS (in-wave coherent)
        float2 bt;
        bt.x = fmaf(t, wta, b1a);
        bt.y = fmaf(t, wtb, b1b);
        *(float2*)&b1t[lane * 2] = bt;

        // z -> bf16 B-fragments
        bf16x8 zB[2];
#pragma unroll
        for (int kt = 0; kt < 2; ++kt) {
            uintx4 u;
            u[0] = pk2(zr[kt * 8 + 0], zr[kt * 8 + 1]);
            u[1] = pk2(zr[kt * 8 + 2], zr[kt * 8 + 3]);
            u[2] = pk2(zr[kt * 8 + 4], zr[kt * 8 + 5]);
            u[3] = pk2(zr[kt * 8 + 6], zr[kt * 8 + 7]);
            zB[kt] = __builtin_bit_cast(bf16x8, u);
        }

        // ---- layer 1: h1^T tiles = WzT * z^T + b1t ----
#pragma unroll
        for (int n0 = 0; n0 < 8; ++n0) {
            f32x4 acc = *(const f32x4*)&b1t[n0 * 16 + q * 4];   // broadcast read
#pragma unroll
            for (int kt = 0; kt < 2; ++kt) {
                bf16x8 wf = __builtin_bit_cast(
                    bf16x8, *(const ushort8*)&WzL[(n0 * 16 + b) * 72 + kt * 32 + q * 8]);
                acc = __builtin_amdgcn_mfma_f32_16x16x32_bf16(wf, zB[kt], acc, 0, 0, 0);
            }
            uintx2 pw;
            pw[0] = pk2(fast_tanh(acc[0]), fast_tanh(acc[1]));
            pw[1] = pk2(fast_tanh(acc[2]), fast_tanh(acc[3]));
            *(uintx2*)&hw[b * 136 + n0 * 16 + q * 4] = pw;      // ds_write_b64
        }

        // ---- layer 2: h2^T = W2T * h1^T + b2 ----
        bf16x8 hB[4];
#pragma unroll
        for (int kt = 0; kt < 4; ++kt)
            hB[kt] = __builtin_bit_cast(
                bf16x8, *(const ushort8*)&hw[b * 136 + kt * 32 + q * 8]);
#pragma unroll
        for (int n0 = 0; n0 < 8; ++n0) {
            unsigned pl = b2p[n0 * 2], ph = b2p[n0 * 2 + 1];
            f32x4 acc;
            acc[0] = __uint_as_float(pl << 16);
            acc[1] = __uint_as_float(pl & 0xffff0000u);
            acc[2] = __uint_as_float(ph << 16);
            acc[3] = __uint_as_float(ph & 0xffff0000u);
#pragma unroll
            for (int kt = 0; kt < 4; ++kt)
                acc = __builtin_amdgcn_mfma_f32_16x16x32_bf16(w2f[n0][kt], hB[kt], acc, 0, 0, 0);
            uintx2 pw;
            pw[0] = pk2(fast_tanh(acc[0]), fast_tanh(acc[1]));
            pw[1] = pk2(fast_tanh(acc[2]), fast_tanh(acc[3]));
            *(uintx2*)&hw[b * 136 + n0 * 16 + q * 4] = pw;
        }

        // ---- layer 3: dz^T = W3T * h2^T + b3 ----
        bf16x8 gB[4];
#pragma unroll
        for (int kt = 0; kt < 4; ++kt)
            gB[kt] = __builtin_bit_cast(
                bf16x8, *(const ushort8*)&hw[b * 136 + kt * 32 + q * 8]);
#pragma unroll
        for (int n0 = 0; n0 < 4; ++n0) {
            unsigned pl = b3p[n0 * 2], ph = b3p[n0 * 2 + 1];
            f32x4 acc;
            acc[0] = __uint_as_float(pl << 16);
            acc[1] = __uint_as_float(pl & 0xffff0000u);
            acc[2] = __uint_as_float(ph << 16);
            acc[3] = __uint_as_float(ph & 0xffff0000u);
#pragma unroll
            for (int kt = 0; kt < 4; ++kt) {
                bf16x8 wf = __builtin_bit_cast(
                    bf16x8, *(const ushort8*)&W3L[(n0 * 16 + b) * 136 + kt * 32 + q * 8]);
                acc = __builtin_amdgcn_mfma_f32_16x16x32_bf16(wf, gB[kt], acc, 0, 0, 0);
            }
            uintx2 pw;
            pw[0] = pk2(acc[0], acc[1]);
            pw[1] = pk2(acc[2], acc[3]);
            *(uintx2*)&hw[b * 136 + n0 * 16 + q * 4] = pw;
        }

        // ---- z += dz * actual_dt ----
#pragma unroll
        for (int kt = 0; kt < 2; ++kt) {
            ushort8 dzb = *(const ushort8*)&hw[b * 136 + kt * 32 + q * 8];
#pragma unroll
            for (int j = 0; j < 8; ++j)
                zr[kt * 8 + j] = fmaf(__uint_as_float(((unsigned)dzb[j]) << 16), dtr,
                                      zr[kt * 8 + j]);
        }
    }

    // store final z
#pragma unroll
    for (int kt = 0; kt < 2; ++kt) {
        float4 a, c;
        a.x = zr[kt * 8 + 0]; a.y = zr[kt * 8 + 1]; a.z = zr[kt * 8 + 2]; a.w = zr[kt * 8 + 3];
        c.x = zr[kt * 8 + 4]; c.y = zr[kt * 8 + 5]; c.z = zr[kt * 8 + 6]; c.w = zr[kt * 8 + 7];
        float4* p = (float4*)(out + (size_t)row * 64 + kt * 32 + q * 8);
        p[0] = a; p[1] = c;
    }
}

extern "C" void kernel_launch(void* const* d_in, const int* in_sizes, int n_in,
                              void* d_out, int out_size, void* d_ws, size_t ws_size,
                              hipStream_t stream) {
    const float* z  = (const float*)d_in[0];
    const float* td = (const float*)d_in[1];
    const float* W1 = (const float*)d_in[2];
    const float* b1 = (const float*)d_in[3];
    const float* W2 = (const float*)d_in[4];
    const float* b2 = (const float*)d_in[5];
    const float* W3 = (const float*)d_in[6];
    const float* b3 = (const float*)d_in[7];
    float* out = (float*)d_out;
    (void)in_sizes; (void)n_in; (void)out_size; (void)ws_size;

    hipMemsetAsync(d_ws, 0, 64, stream);
    k_prep<<<64, 256, 0, stream>>>(td, W1, W2, W3, (unsigned*)d_ws);
    k_main<<<1024, 256, 0, stream>>>(z, td, W1, b1, b2, b3, d_ws, out);
}

// Round 3
// 488.046 us; speedup vs baseline: 1.0187x; 1.0187x over previous
//
#include <hip/hip_runtime.h>
#include <hip/hip_bf16.h>

#define B_N 65536

typedef __attribute__((ext_vector_type(8))) __bf16 bf16x8;
typedef __attribute__((ext_vector_type(8))) unsigned short ushort8;
typedef __attribute__((ext_vector_type(4))) float f32x4;
typedef __attribute__((ext_vector_type(2))) unsigned uintx2;
typedef __attribute__((ext_vector_type(4))) unsigned uintx4;

// ---------- ws layout (bytes) ----------
// 0     : unsigned max|time_delta| bits (atomicMax target; memset to 0 first)
// 64    : WzT  bf16 [128][64]   Wz = W1[0:64,:] transposed
// 16448 : W2T  bf16 [128][128]
// 49216 : W3T  bf16 [64][128]

__device__ __forceinline__ unsigned short f2bf(float f) {
    unsigned u = __float_as_uint(f);
    u += 0x7FFFu + ((u >> 16) & 1u);   // RNE
    return (unsigned short)(u >> 16);
}

#if defined(__has_builtin)
#if __has_builtin(__builtin_amdgcn_cvt_pk_bf16_f32)
#define HAVE_PK_BF16 1
#endif
#endif

#ifdef HAVE_PK_BF16
__device__ __forceinline__ unsigned pk2(float a, float b) {
    return __builtin_bit_cast(unsigned, __builtin_amdgcn_cvt_pk_bf16_f32(a, b));
}
#else
__device__ __forceinline__ unsigned pk2(float a, float b) {
    return (unsigned)f2bf(a) | ((unsigned)f2bf(b) << 16);
}
#endif

__device__ __forceinline__ float fast_tanh(float x) {
    float e = __expf(2.0f * x);
    return fmaf(-2.0f, __builtin_amdgcn_rcpf(e + 1.0f), 1.0f);
}

// ---------- kernel 1: fused max|td| reduction + weight transpose to bf16 ----------
__global__ void k_prep(const float* __restrict__ td, const float* __restrict__ W1,
                       const float* __restrict__ W2, const float* __restrict__ W3,
                       unsigned* __restrict__ ws) {
    const int stride = gridDim.x * blockDim.x;
    int i0 = blockIdx.x * blockDim.x + threadIdx.x;

    float m = 0.0f;
    for (int i = i0; i < B_N; i += stride) m = fmaxf(m, fabsf(td[i]));
#pragma unroll
    for (int o = 32; o; o >>= 1) m = fmaxf(m, __shfl_down(m, o));
    if ((threadIdx.x & 63) == 0) atomicMax(ws, __float_as_uint(m));

    unsigned short* wsb = (unsigned short*)((char*)ws + 64);
    const int total = 8192 + 16384 + 8192;
    for (int i = i0; i < total; i += stride) {
        float v;
        int o = i;
        if (o < 8192) {                       // WzT[n][k] = W1[k][n]
            int n = o >> 6, k = o & 63;
            v = W1[k * 128 + n];
        } else if (o < 8192 + 16384) {        // W2T[n][k] = W2[k][n]
            o -= 8192;
            int n = o >> 7, k = o & 127;
            v = W2[k * 128 + n];
        } else {                              // W3T[n][k] = W3[k][n]
            o -= 8192 + 16384;
            int n = o >> 7, k = o & 127;
            v = W3[k * 64 + n];
        }
        wsb[i] = f2bf(v);
    }
}

// ---------- kernel 2: the ODE solver ----------
// block = 256 = 4 waves; wave owns 16 rows; grid = 65536/64 = 1024
// Transposed-domain MFMA: D = Wfrag(A) * act(B) -> D[neuron][batch]
// => lane (b = lane&15) holds 4 CONSECUTIVE neurons (q*4+r) per 16-tile:
//    packed cvt + ds_write_b64 instead of 4 scalar b16 writes.
// Register budget note: launch_bounds(256,2) => 256 unified VGPR+AGPR/wave.
// w2f cache = 128 regs; biases MUST stay in LDS (R2 spilled with them in regs).
__launch_bounds__(256, 2)
__global__ void k_main(const float* __restrict__ z_in, const float* __restrict__ td,
                       const float* __restrict__ W1, const float* __restrict__ b1,
                       const float* __restrict__ b2, const float* __restrict__ b3,
                       const void* __restrict__ ws, float* __restrict__ out) {
    __shared__ __align__(16) unsigned short WzL[128 * 72];    // 18432 B
    __shared__ __align__(16) unsigned short W3L[64 * 136];    // 17408 B
    __shared__ __align__(16) unsigned short hS[4][16 * 136];  // 17408 B (per-wave)
    __shared__ __align__(16) float b1tW[4][128];              // 2048 B (per-wave)
    __shared__ __align__(16) float b2L[128];                  // 512 B
    __shared__ __align__(16) float b3L[64];                   // 256 B

    const unsigned* wsu = (const unsigned*)ws;
    const unsigned short* wzg = (const unsigned short*)((const char*)ws + 64);
    const unsigned short* w2g = wzg + 8192;
    const unsigned short* w3g = wzg + 24576;

    const int tid = threadIdx.x;

    for (int c = tid; c < 1024; c += 256) {          // stage WzT
        int n = c >> 3, k8 = (c & 7) << 3;
        *(ushort8*)&WzL[n * 72 + k8] = *(const ushort8*)&wzg[n * 64 + k8];
    }
    for (int c = tid; c < 1024; c += 256) {          // stage W3T
        int n = c >> 4, k8 = (c & 15) << 3;
        *(ushort8*)&W3L[n * 136 + k8] = *(const ushort8*)&w3g[n * 128 + k8];
    }
    if (tid < 128) b2L[tid] = b2[tid];
    if (tid < 64)  b3L[tid] = b3[tid];
    __syncthreads();

    const float maxab = __uint_as_float(wsu[0]);
    const int steps = (int)ceil((double)maxab / 0.1);

    const int wave = tid >> 6;
    const int lane = tid & 63;
    const int q = lane >> 4;
    const int b = lane & 15;                  // batch row (B/C/D) == weight row (A)
    const int row = blockIdx.x * 64 + wave * 16 + b;
    unsigned short* hw = hS[wave];
    float* b1t = b1tW[wave];

    // z state in fp32, B-fragment layout: zr[kt*8+j] = z[row][kt*32 + q*8 + j]
    float zr[16];
#pragma unroll
    for (int kt = 0; kt < 2; ++kt) {
        const float4* p = (const float4*)(z_in + (size_t)row * 64 + kt * 32 + q * 8);
        float4 a = p[0], c = p[1];
        zr[kt * 8 + 0] = a.x; zr[kt * 8 + 1] = a.y; zr[kt * 8 + 2] = a.z; zr[kt * 8 + 3] = a.w;
        zr[kt * 8 + 4] = c.x; zr[kt * 8 + 5] = c.y; zr[kt * 8 + 6] = c.z; zr[kt * 8 + 7] = c.w;
    }
    const float dtr = (steps > 0) ? (td[row] / (float)steps) : 0.0f;

    // W2T A-fragments cached in registers/AGPRs (32 frags * 4 regs = 128)
    bf16x8 w2f[8][4];
#pragma unroll
    for (int n0 = 0; n0 < 8; ++n0)
#pragma unroll
        for (int kt = 0; kt < 4; ++kt)
            w2f[n0][kt] = __builtin_bit_cast(
                bf16x8, *(const ushort8*)&w2g[(n0 * 16 + b) * 128 + kt * 32 + q * 8]);

    // layer-1 bias: this lane owns entries 2*lane, 2*lane+1 of b1t
    const float b1a = b1[lane * 2], b1b = b1[lane * 2 + 1];
    const float wta = W1[64 * 128 + lane * 2], wtb = W1[64 * 128 + lane * 2 + 1];

    for (int s = 0; s < steps; ++s) {
        const float t = (float)s * 0.1f;

        // per-step layer-1 bias vector into per-wave LDS (in-wave coherent)
        float2 bt;
        bt.x = fmaf(t, wta, b1a);
        bt.y = fmaf(t, wtb, b1b);
        *(float2*)&b1t[lane * 2] = bt;

        // z -> bf16 B-fragments
        bf16x8 zB[2];
#pragma unroll
        for (int kt = 0; kt < 2; ++kt) {
            uintx4 u;
            u[0] = pk2(zr[kt * 8 + 0], zr[kt * 8 + 1]);
            u[1] = pk2(zr[kt * 8 + 2], zr[kt * 8 + 3]);
            u[2] = pk2(zr[kt * 8 + 4], zr[kt * 8 + 5]);
            u[3] = pk2(zr[kt * 8 + 6], zr[kt * 8 + 7]);
            zB[kt] = __builtin_bit_cast(bf16x8, u);
        }

        // ---- layer 1: h1^T tiles = WzT * z^T + b1t ----
#pragma unroll
        for (int n0 = 0; n0 < 8; ++n0) {
            f32x4 acc = *(const f32x4*)&b1t[n0 * 16 + q * 4];   // broadcast read
#pragma unroll
            for (int kt = 0; kt < 2; ++kt) {
                bf16x8 wf = __builtin_bit_cast(
                    bf16x8, *(const ushort8*)&WzL[(n0 * 16 + b) * 72 + kt * 32 + q * 8]);
                acc = __builtin_amdgcn_mfma_f32_16x16x32_bf16(wf, zB[kt], acc, 0, 0, 0);
            }
            uintx2 pw;
            pw[0] = pk2(fast_tanh(acc[0]), fast_tanh(acc[1]));
            pw[1] = pk2(fast_tanh(acc[2]), fast_tanh(acc[3]));
            *(uintx2*)&hw[b * 136 + n0 * 16 + q * 4] = pw;      // ds_write_b64
        }

        // ---- layer 2: h2^T = W2T * h1^T + b2 ----
        bf16x8 hB[4];
#pragma unroll
        for (int kt = 0; kt < 4; ++kt)
            hB[kt] = __builtin_bit_cast(
                bf16x8, *(const ushort8*)&hw[b * 136 + kt * 32 + q * 8]);
#pragma unroll
        for (int n0 = 0; n0 < 8; ++n0) {
            f32x4 acc = *(const f32x4*)&b2L[n0 * 16 + q * 4];   // broadcast read
#pragma unroll
            for (int kt = 0; kt < 4; ++kt)
                acc = __builtin_amdgcn_mfma_f32_16x16x32_bf16(w2f[n0][kt], hB[kt], acc, 0, 0, 0);
            uintx2 pw;
            pw[0] = pk2(fast_tanh(acc[0]), fast_tanh(acc[1]));
            pw[1] = pk2(fast_tanh(acc[2]), fast_tanh(acc[3]));
            *(uintx2*)&hw[b * 136 + n0 * 16 + q * 4] = pw;
        }

        // ---- layer 3: dz^T = W3T * h2^T + b3 ----
        bf16x8 gB[4];
#pragma unroll
        for (int kt = 0; kt < 4; ++kt)
            gB[kt] = __builtin_bit_cast(
                bf16x8, *(const ushort8*)&hw[b * 136 + kt * 32 + q * 8]);
#pragma unroll
        for (int n0 = 0; n0 < 4; ++n0) {
            f32x4 acc = *(const f32x4*)&b3L[n0 * 16 + q * 4];   // broadcast read
#pragma unroll
            for (int kt = 0; kt < 4; ++kt) {
                bf16x8 wf = __builtin_bit_cast(
                    bf16x8, *(const ushort8*)&W3L[(n0 * 16 + b) * 136 + kt * 32 + q * 8]);
                acc = __builtin_amdgcn_mfma_f32_16x16x32_bf16(wf, gB[kt], acc, 0, 0, 0);
            }
            uintx2 pw;
            pw[0] = pk2(acc[0], acc[1]);
            pw[1] = pk2(acc[2], acc[3]);
            *(uintx2*)&hw[b * 136 + n0 * 16 + q * 4] = pw;
        }

        // ---- z += dz * actual_dt ----
#pragma unroll
        for (int kt = 0; kt < 2; ++kt) {
            ushort8 dzb = *(const ushort8*)&hw[b * 136 + kt * 32 + q * 8];
#pragma unroll
            for (int j = 0; j < 8; ++j)
                zr[kt * 8 + j] = fmaf(__uint_as_float(((unsigned)dzb[j]) << 16), dtr,
                                      zr[kt * 8 + j]);
        }
    }

    // store final z
#pragma unroll
    for (int kt = 0; kt < 2; ++kt) {
        float4 a, c;
        a.x = zr[kt * 8 + 0]; a.y = zr[kt * 8 + 1]; a.z = zr[kt * 8 + 2]; a.w = zr[kt * 8 + 3];
        c.x = zr[kt * 8 + 4]; c.y = zr[kt * 8 + 5]; c.z = zr[kt * 8 + 6]; c.w = zr[kt * 8 + 7];
        float4* p = (float4*)(out + (size_t)row * 64 + kt * 32 + q * 8);
        p[0] = a; p[1] = c;
    }
}

extern "C" void kernel_launch(void* const* d_in, const int* in_sizes, int n_in,
                              void* d_out, int out_size, void* d_ws, size_t ws_size,
                              hipStream_t stream) {
    const float* z  = (const float*)d_in[0];
    const float* td = (const float*)d_in[1];
    const float* W1 = (const float*)d_in[2];
    const float* b1 = (const float*)d_in[3];
    const float* W2 = (const float*)d_in[4];
    const float* b2 = (const float*)d_in[5];
    const float* W3 = (const float*)d_in[6];
    const float* b3 = (const float*)d_in[7];
    float* out = (float*)d_out;
    (void)in_sizes; (void)n_in; (void)out_size; (void)ws_size;

    hipMemsetAsync(d_ws, 0, 64, stream);
    k_prep<<<64, 256, 0, stream>>>(td, W1, W2, W3, (unsigned*)d_ws);
    k_main<<<1024, 256, 0, stream>>>(z, td, W1, b1, b2, b3, d_ws, out);
}

// Round 5
// 271.519 us; speedup vs baseline: 1.8311x; 1.7975x over previous
//
#include <hip/hip_runtime.h>
#include <hip/hip_bf16.h>

#define B_N 65536

typedef __attribute__((ext_vector_type(8))) __bf16 bf16x8;
typedef __attribute__((ext_vector_type(8))) unsigned short ushort8;
typedef __attribute__((ext_vector_type(4))) float f32x4;
typedef __attribute__((ext_vector_type(2))) unsigned uintx2;
typedef __attribute__((ext_vector_type(4))) unsigned uintx4;

// ---------- ws layout (bytes) ----------
// 0     : unsigned max|time_delta| bits (atomicMax target; memset to 0 first)
// 64    : WzT  bf16 [128][64]   Wz = W1[0:64,:] transposed
// 16448 : W2T  bf16 [128][128]
// 49216 : W3T  bf16 [64][128]

__device__ __forceinline__ unsigned short f2bf(float f) {
    unsigned u = __float_as_uint(f);
    u += 0x7FFFu + ((u >> 16) & 1u);   // RNE
    return (unsigned short)(u >> 16);
}

#if defined(__has_builtin)
#if __has_builtin(__builtin_amdgcn_cvt_pk_bf16_f32)
#define HAVE_PK_BF16 1
#endif
#endif

#ifdef HAVE_PK_BF16
__device__ __forceinline__ unsigned pk2(float a, float b) {
    return __builtin_bit_cast(unsigned, __builtin_amdgcn_cvt_pk_bf16_f32(a, b));
}
#else
__device__ __forceinline__ unsigned pk2(float a, float b) {
    return (unsigned)f2bf(a) | ((unsigned)f2bf(b) << 16);
}
#endif

__device__ __forceinline__ float fast_tanh(float x) {
    float e = __expf(2.0f * x);
    return fmaf(-2.0f, __builtin_amdgcn_rcpf(e + 1.0f), 1.0f);
}

// Layer-2 K-chain: 4 dependent MFMAs accumulating into acc, A operands FORCED
// into AGPRs ("a" constraint) so the loop-invariant W2 cache lives in the
// accumulator file (R2/R3: compiler kept it in scratch -> 1.2 GB/dispatch).
// R4 lesson: inline asm bypasses the hazard recognizer -- the MFMA->VALU-read
// wait states MUST be emitted manually, hence the trailing s_nop 7 x2 (16
// wait states covers the worst CDNA4 MFMA write -> VALU read requirement).
// Back-to-back same-D MFMA accumulation needs no nops (standard hand-asm GEMM).
__device__ __forceinline__ void mfma4_w2(f32x4& acc,
                                         const bf16x8& a0, const bf16x8& a1,
                                         const bf16x8& a2, const bf16x8& a3,
                                         const bf16x8& b0, const bf16x8& b1,
                                         const bf16x8& b2, const bf16x8& b3) {
    asm("v_mfma_f32_16x16x32_bf16 %0, %1, %5, %0\n\t"
        "v_mfma_f32_16x16x32_bf16 %0, %2, %6, %0\n\t"
        "v_mfma_f32_16x16x32_bf16 %0, %3, %7, %0\n\t"
        "v_mfma_f32_16x16x32_bf16 %0, %4, %8, %0\n\t"
        "s_nop 7\n\t"
        "s_nop 7"
        : "+v"(acc)
        : "a"(a0), "a"(a1), "a"(a2), "a"(a3),
          "v"(b0), "v"(b1), "v"(b2), "v"(b3));
}

// ---------- kernel 1: fused max|td| reduction + weight transpose to bf16 ----------
__global__ void k_prep(const float* __restrict__ td, const float* __restrict__ W1,
                       const float* __restrict__ W2, const float* __restrict__ W3,
                       unsigned* __restrict__ ws) {
    const int stride = gridDim.x * blockDim.x;
    int i0 = blockIdx.x * blockDim.x + threadIdx.x;

    float m = 0.0f;
    for (int i = i0; i < B_N; i += stride) m = fmaxf(m, fabsf(td[i]));
#pragma unroll
    for (int o = 32; o; o >>= 1) m = fmaxf(m, __shfl_down(m, o));
    if ((threadIdx.x & 63) == 0) atomicMax(ws, __float_as_uint(m));

    unsigned short* wsb = (unsigned short*)((char*)ws + 64);
    const int total = 8192 + 16384 + 8192;
    for (int i = i0; i < total; i += stride) {
        float v;
        int o = i;
        if (o < 8192) {                       // WzT[n][k] = W1[k][n]
            int n = o >> 6, k = o & 63;
            v = W1[k * 128 + n];
        } else if (o < 8192 + 16384) {        // W2T[n][k] = W2[k][n]
            o -= 8192;
            int n = o >> 7, k = o & 127;
            v = W2[k * 128 + n];
        } else {                              // W3T[n][k] = W3[k][n]
            o -= 8192 + 16384;
            int n = o >> 7, k = o & 127;
            v = W3[k * 64 + n];
        }
        wsb[i] = f2bf(v);
    }
}

// ---------- kernel 2: the ODE solver ----------
// block = 256 = 4 waves; wave owns 16 rows; grid = 65536/64 = 1024
// Transposed-domain MFMA: D = Wfrag(A) * act(B) -> D[neuron][batch]
// => lane (b = lane&15) holds 4 CONSECUTIVE neurons per 16-tile:
//    packed cvt + ds_write_b64 instead of 4 scalar b16 writes.
__launch_bounds__(256, 2)
__global__ void k_main(const float* __restrict__ z_in, const float* __restrict__ td,
                       const float* __restrict__ W1, const float* __restrict__ b1,
                       const float* __restrict__ b2, const float* __restrict__ b3,
                       const void* __restrict__ ws, float* __restrict__ out) {
    __shared__ __align__(16) unsigned short WzL[128 * 72];    // 18432 B
    __shared__ __align__(16) unsigned short W3L[64 * 136];    // 17408 B
    __shared__ __align__(16) unsigned short hS[4][16 * 136];  // 17408 B (per-wave)
    __shared__ __align__(16) float b1tW[4][128];              // 2048 B (per-wave)
    __shared__ __align__(16) float4 pb1wtL[64];               // 1024 B {b1 pair, wt pair}
    __shared__ __align__(16) float b2L[128];                  // 512 B
    __shared__ __align__(16) float b3L[64];                   // 256 B

    const unsigned* wsu = (const unsigned*)ws;
    const unsigned short* wzg = (const unsigned short*)((const char*)ws + 64);
    const unsigned short* w2g = wzg + 8192;
    const unsigned short* w3g = wzg + 24576;

    const int tid = threadIdx.x;

    for (int c = tid; c < 1024; c += 256) {          // stage WzT
        int n = c >> 3, k8 = (c & 7) << 3;
        *(ushort8*)&WzL[n * 72 + k8] = *(const ushort8*)&wzg[n * 64 + k8];
    }
    for (int c = tid; c < 1024; c += 256) {          // stage W3T
        int n = c >> 4, k8 = (c & 15) << 3;
        *(ushort8*)&W3L[n * 136 + k8] = *(const ushort8*)&w3g[n * 128 + k8];
    }
    if (tid < 128) b2L[tid] = b2[tid];
    if (tid < 64)  b3L[tid] = b3[tid];
    if (tid < 64) {
        float4 p;
        p.x = b1[tid * 2];
        p.y = b1[tid * 2 + 1];
        p.z = W1[64 * 128 + tid * 2];     // Wt = last row of W1
        p.w = W1[64 * 128 + tid * 2 + 1];
        pb1wtL[tid] = p;
    }
    __syncthreads();

    const float maxab = __uint_as_float(wsu[0]);
    const int steps = (int)ceil((double)maxab / 0.1);

    const int wave = tid >> 6;
    const int lane = tid & 63;
    const int q = lane >> 4;
    const int b = lane & 15;                  // batch row (B/C/D) == weight row (A)
    const int row = blockIdx.x * 64 + wave * 16 + b;
    unsigned short* hw = hS[wave];
    float* b1t = b1tW[wave];

    // z state in fp32, B-fragment layout: zr[kt*8+j] = z[row][kt*32 + q*8 + j]
    float zr[16];
#pragma unroll
    for (int kt = 0; kt < 2; ++kt) {
        const float4* p = (const float4*)(z_in + (size_t)row * 64 + kt * 32 + q * 8);
        float4 a = p[0], c = p[1];
        zr[kt * 8 + 0] = a.x; zr[kt * 8 + 1] = a.y; zr[kt * 8 + 2] = a.z; zr[kt * 8 + 3] = a.w;
        zr[kt * 8 + 4] = c.x; zr[kt * 8 + 5] = c.y; zr[kt * 8 + 6] = c.z; zr[kt * 8 + 7] = c.w;
    }
    const float dtr = (steps > 0) ? (td[row] / (float)steps) : 0.0f;

    // W2T A-fragments, pinned to AGPRs via the "a"-constraint MFMA
    bf16x8 w2f[8][4];
#pragma unroll
    for (int n0 = 0; n0 < 8; ++n0)
#pragma unroll
        for (int kt = 0; kt < 4; ++kt)
            w2f[n0][kt] = __builtin_bit_cast(
                bf16x8, *(const ushort8*)&w2g[(n0 * 16 + b) * 128 + kt * 32 + q * 8]);

    for (int s = 0; s < steps; ++s) {
        const float t = (float)s * 0.1f;

        // per-step layer-1 bias vector into per-wave LDS (in-wave coherent)
        {
            float4 pb = pb1wtL[lane];
            float2 bt;
            bt.x = fmaf(t, pb.z, pb.x);
            bt.y = fmaf(t, pb.w, pb.y);
            *(float2*)&b1t[lane * 2] = bt;
        }

        // z -> bf16 B-fragments
        bf16x8 zB[2];
#pragma unroll
        for (int kt = 0; kt < 2; ++kt) {
            uintx4 u;
            u[0] = pk2(zr[kt * 8 + 0], zr[kt * 8 + 1]);
            u[1] = pk2(zr[kt * 8 + 2], zr[kt * 8 + 3]);
            u[2] = pk2(zr[kt * 8 + 4], zr[kt * 8 + 5]);
            u[3] = pk2(zr[kt * 8 + 6], zr[kt * 8 + 7]);
            zB[kt] = __builtin_bit_cast(bf16x8, u);
        }

        // ---- layer 1: h1^T tiles = WzT * z^T + b1t ----
#pragma unroll
        for (int n0 = 0; n0 < 8; ++n0) {
            f32x4 acc = *(const f32x4*)&b1t[n0 * 16 + q * 4];   // broadcast read
#pragma unroll
            for (int kt = 0; kt < 2; ++kt) {
                bf16x8 wf = __builtin_bit_cast(
                    bf16x8, *(const ushort8*)&WzL[(n0 * 16 + b) * 72 + kt * 32 + q * 8]);
                acc = __builtin_amdgcn_mfma_f32_16x16x32_bf16(wf, zB[kt], acc, 0, 0, 0);
            }
            uintx2 pw;
            pw[0] = pk2(fast_tanh(acc[0]), fast_tanh(acc[1]));
            pw[1] = pk2(fast_tanh(acc[2]), fast_tanh(acc[3]));
            *(uintx2*)&hw[b * 136 + n0 * 16 + q * 4] = pw;      // ds_write_b64
        }

        // ---- layer 2: h2^T = W2T * h1^T + b2  (W2 frags from AGPRs) ----
        bf16x8 hB[4];
#pragma unroll
        for (int kt = 0; kt < 4; ++kt)
            hB[kt] = __builtin_bit_cast(
                bf16x8, *(const ushort8*)&hw[b * 136 + kt * 32 + q * 8]);
#pragma unroll
        for (int n0 = 0; n0 < 8; ++n0) {
            f32x4 acc = *(const f32x4*)&b2L[n0 * 16 + q * 4];   // broadcast read
            mfma4_w2(acc, w2f[n0][0], w2f[n0][1], w2f[n0][2], w2f[n0][3],
                     hB[0], hB[1], hB[2], hB[3]);
            uintx2 pw;
            pw[0] = pk2(fast_tanh(acc[0]), fast_tanh(acc[1]));
            pw[1] = pk2(fast_tanh(acc[2]), fast_tanh(acc[3]));
            *(uintx2*)&hw[b * 136 + n0 * 16 + q * 4] = pw;
        }

        // ---- layer 3: dz^T = W3T * h2^T + b3 ----
        bf16x8 gB[4];
#pragma unroll
        for (int kt = 0; kt < 4; ++kt)
            gB[kt] = __builtin_bit_cast(
                bf16x8, *(const ushort8*)&hw[b * 136 + kt * 32 + q * 8]);
#pragma unroll
        for (int n0 = 0; n0 < 4; ++n0) {
            f32x4 acc = *(const f32x4*)&b3L[n0 * 16 + q * 4];   // broadcast read
#pragma unroll
            for (int kt = 0; kt < 4; ++kt) {
                bf16x8 wf = __builtin_bit_cast(
                    bf16x8, *(const ushort8*)&W3L[(n0 * 16 + b) * 136 + kt * 32 + q * 8]);
                acc = __builtin_amdgcn_mfma_f32_16x16x32_bf16(wf, gB[kt], acc, 0, 0, 0);
            }
            uintx2 pw;
            pw[0] = pk2(acc[0], acc[1]);
            pw[1] = pk2(acc[2], acc[3]);
            *(uintx2*)&hw[b * 136 + n0 * 16 + q * 4] = pw;
        }

        // ---- z += dz * actual_dt ----
#pragma unroll
        for (int kt = 0; kt < 2; ++kt) {
            ushort8 dzb = *(const ushort8*)&hw[b * 136 + kt * 32 + q * 8];
#pragma unroll
            for (int j = 0; j < 8; ++j)
                zr[kt * 8 + j] = fmaf(__uint_as_float(((unsigned)dzb[j]) << 16), dtr,
                                      zr[kt * 8 + j]);
        }
    }

    // store final z
#pragma unroll
    for (int kt = 0; kt < 2; ++kt) {
        float4 a, c;
        a.x = zr[kt * 8 + 0]; a.y = zr[kt * 8 + 1]; a.z = zr[kt * 8 + 2]; a.w = zr[kt * 8 + 3];
        c.x = zr[kt * 8 + 4]; c.y = zr[kt * 8 + 5]; c.z = zr[kt * 8 + 6]; c.w = zr[kt * 8 + 7];
        float4* p = (float4*)(out + (size_t)row * 64 + kt * 32 + q * 8);
        p[0] = a; p[1] = c;
    }
}

extern "C" void kernel_launch(void* const* d_in, const int* in_sizes, int n_in,
                              void* d_out, int out_size, void* d_ws, size_t ws_size,
                              hipStream_t stream) {
    const float* z  = (const float*)d_in[0];
    const float* td = (const float*)d_in[1];
    const float* W1 = (const float*)d_in[2];
    const float* b1 = (const float*)d_in[3];
    const float* W2 = (const float*)d_in[4];
    const float* b2 = (const float*)d_in[5];
    const float* W3 = (const float*)d_in[6];
    const float* b3 = (const float*)d_in[7];
    float* out = (float*)d_out;
    (void)in_sizes; (void)n_in; (void)out_size; (void)ws_size;

    hipMemsetAsync(d_ws, 0, 64, stream);
    k_prep<<<64, 256, 0, stream>>>(td, W1, W2, W3, (unsigned*)d_ws);
    k_main<<<1024, 256, 0, stream>>>(z, td, W1, b1, b2, b3, d_ws, out);
}